// Round 15
// baseline (64.829 us; speedup 1.0000x reference)
//
#include <hip/hip_runtime.h>

// ---------------------------------------------------------------------------
// AtomicLinear == x @ W^T + bias.  M=8192, N=2048, K=2048, fp32 in/out.
// R13 = R12 + XCD-locality block mapping (single-lever experiment).
// R12: 128x128 tile, 4 waves, 2-barrier loop, global_load_lds staging,
// v_mfma_i32_16x16x64_i8 (16 K-tiles), per-row symmetric int8 quant prepass,
// swizzled tile images (slot = chunk ^ (row&7), 0 bank conflicts).
// R13 mapping: xcd = bid&7 owns A-panels mt in [xcd*8, xcd*8+8); nt-major
// order inside the XCD keeps the hot B panel (256 KB) + 8 A panels (2 MB)
// L2-resident -> expected FETCH_SIZE 70 MB -> 25-40 MB.
// ---------------------------------------------------------------------------

typedef int i32x4 __attribute__((ext_vector_type(4)));

static constexpr int Mdim = 8192, Ndim = 2048, Kdim = 2048;
static constexpr int KT = 16;            // K-tiles of 128 i8
static constexpr int TB = 16384;         // tile: 128 rows x 128 i8

// ---------------------------------------------------------------------------
// Fused quant prepass (validated R12): block row < Mdim -> xa, else -> wbf.
// Tile (rt,kt): 16 KB; row r is prow r (128 B); chunk c at slot = c ^ (r&7).
// ---------------------------------------------------------------------------
__global__ void quantAB(const float* __restrict__ x, const float* __restrict__ w,
                        signed char* __restrict__ xa, signed char* __restrict__ wbf,
                        float* __restrict__ sx, float* __restrict__ sw) {
    const int rowg = blockIdx.x;
    const bool isA = rowg < Mdim;
    const int row  = isA ? rowg : rowg - Mdim;
    const float* src = (isA ? x : w) + (size_t)row * 2048;
    signed char* dst = isA ? xa : wbf;
    float* scale     = isA ? sx : sw;

    const int j = threadIdx.x;               // 0..255, elems k0 = j*8
    const int lane = j & 63, wid = j >> 6;
    const float* p = src + j * 8;
    float4 v0 = *(const float4*)p;
    float4 v1 = *(const float4*)(p + 4);
    float m = fmaxf(fmaxf(fmaxf(fabsf(v0.x), fabsf(v0.y)), fmaxf(fabsf(v0.z), fabsf(v0.w))),
                    fmaxf(fmaxf(fabsf(v1.x), fabsf(v1.y)), fmaxf(fabsf(v1.z), fabsf(v1.w))));
#pragma unroll
    for (int i = 1; i < 64; i <<= 1) m = fmaxf(m, __shfl_xor(m, i));
    __shared__ float wm[4];
    if (lane == 0) wm[wid] = m;
    __syncthreads();
    const float rm = fmaxf(fmaxf(wm[0], wm[1]), fmaxf(wm[2], wm[3]));
    const float qs = rm > 1e-30f ? 127.0f / rm : 0.0f;
    if (j == 0) scale[row] = rm > 1e-30f ? rm * (1.0f / 127.0f) : 0.0f;

    int q[8];
    q[0] = __float2int_rn(v0.x * qs); q[1] = __float2int_rn(v0.y * qs);
    q[2] = __float2int_rn(v0.z * qs); q[3] = __float2int_rn(v0.w * qs);
    q[4] = __float2int_rn(v1.x * qs); q[5] = __float2int_rn(v1.y * qs);
    q[6] = __float2int_rn(v1.z * qs); q[7] = __float2int_rn(v1.w * qs);
    uint2 pk;
    pk.x = (q[0] & 255) | ((q[1] & 255) << 8) | ((q[2] & 255) << 16) | ((unsigned)(q[3] & 255) << 24);
    pk.y = (q[4] & 255) | ((q[5] & 255) << 8) | ((q[6] & 255) << 16) | ((unsigned)(q[7] & 255) << 24);

    const int rt = row >> 7, r = row & 127;
    const int kt = j >> 4;
    const int c  = (j & 15) >> 1;            // 16B chunk within K-tile
    const int b8 = (j & 1) * 8;
    size_t byte = (size_t)(rt * 16 + kt) * TB + r * 128 +
                  (((unsigned)(c ^ (r & 7))) << 4) + b8;
    *(uint2*)(dst + byte) = pk;
}

#define GL_LDS16(gsrc, ldst)                                                    \
    __builtin_amdgcn_global_load_lds(                                           \
        (const __attribute__((address_space(1))) void*)(gsrc),                  \
        (__attribute__((address_space(3))) void*)(ldst), 16, 0, 0)

// 128x128 tile, 256 threads (4 waves 2M x 2N), wave tile 64x64.
// R12's 2-barrier loop; R13 changes ONLY the bid -> (mt,nt) mapping.
__global__ __launch_bounds__(256) void gemm13(
    const signed char* __restrict__ xa, const signed char* __restrict__ wbf,
    const float* __restrict__ sx, const float* __restrict__ sw,
    const float* __restrict__ bias, float* __restrict__ out) {
    __shared__ signed char sA[TB];
    __shared__ signed char sB[TB];

    const int tid  = threadIdx.x;
    const int lane = tid & 63, wid = tid >> 6;
    const int wr   = wid >> 1;               // 0..1
    const int wc   = wid & 1;                // 0..1
    const int fr   = lane & 15, fq = lane >> 4;

    // R13 XCD-locality mapping: xcd owns A-panels [xcd*8, xcd*8+8); nt-major.
    const int bid = blockIdx.x;              // 1024 blocks
    const int xcd = bid & 7;
    const int s   = bid >> 3;                // 0..127
    const int nt  = s >> 3;                  // 0..15
    const int mt  = xcd * 8 + (s & 7);       // 0..63

    const signed char* aP = xa + (size_t)mt * KT * TB;
    const signed char* bP = wbf + (size_t)nt * KT * TB;

    // slot = chunk ^ (fr&7): row-independent per lane (row%8 == fr%8).
    const int so0 = (fq ^ (fr & 7)) << 4;            // kk = 0
    const int so1 = ((4 + fq) ^ (fr & 7)) << 4;      // kk = 1
    const int aBase = (wr * 64 + fr) * 128;
    const int bBase = (wc * 64 + fr) * 128;

    i32x4 acc[4][4];
#pragma unroll
    for (int i = 0; i < 4; ++i)
#pragma unroll
        for (int j = 0; j < 4; ++j)
            acc[i][j] = i32x4{0, 0, 0, 0};

    for (int t = 0; t < KT; ++t) {
        __syncthreads();                     // previous tile's reads complete
        {
            const signed char* gA = aP + (size_t)t * TB + tid * 16;
            const signed char* gB = bP + (size_t)t * TB + tid * 16;
#pragma unroll
            for (int q = 0; q < 4; ++q) {
                GL_LDS16(gA + q * 4096, sA + q * 4096 + tid * 16);
                GL_LDS16(gB + q * 4096, sB + q * 4096 + tid * 16);
            }
        }
        __syncthreads();                     // implies vmcnt(0): tile resident

#pragma unroll
        for (int kk = 0; kk < 2; ++kk) {
            const int so = kk ? so1 : so0;
            i32x4 a[4], b[4];
#pragma unroll
            for (int mi = 0; mi < 4; ++mi)
                a[mi] = *(const i32x4*)(sA + aBase + mi * 2048 + so);
#pragma unroll
            for (int ni = 0; ni < 4; ++ni)
                b[ni] = *(const i32x4*)(sB + bBase + ni * 2048 + so);
#pragma unroll
            for (int mi = 0; mi < 4; ++mi)
#pragma unroll
                for (int ni = 0; ni < 4; ++ni)
                    asm volatile("v_mfma_i32_16x16x64_i8 %0, %1, %2, %0"
                                 : "+a"(acc[mi][ni]) : "v"(a[mi]), "v"(b[ni]));
        }
    }

    // Epilogue: row = mt*128 + wr*64 + mi*16 + fq*4 + rr;
    //           col = nt*128 + wc*64 + ni*16 + fr.
    const int gr0 = mt * 128 + wr * 64 + fq * 4;
    const int gc0 = nt * 128 + wc * 64;
#pragma unroll
    for (int ni = 0; ni < 4; ++ni) {
        const int cn = gc0 + ni * 16 + fr;
        const float tv = sw[cn];
        const float bv = bias[cn];
#pragma unroll
        for (int mi = 0; mi < 4; ++mi) {
            const int rm = gr0 + mi * 16;
            const float4 sv = *(const float4*)&sx[rm];
            out[(size_t)(rm + 0) * Ndim + cn] = (float)acc[mi][ni][0] * sv.x * tv + bv;
            out[(size_t)(rm + 1) * Ndim + cn] = (float)acc[mi][ni][1] * sv.y * tv + bv;
            out[(size_t)(rm + 2) * Ndim + cn] = (float)acc[mi][ni][2] * sv.z * tv + bv;
            out[(size_t)(rm + 3) * Ndim + cn] = (float)acc[mi][ni][3] * sv.w * tv + bv;
        }
    }
}

// Correct-but-slow fp32 fallback if workspace is too small.
__global__ void fallback_gemm(const float* __restrict__ x, const float* __restrict__ w,
                              const float* __restrict__ bias, float* __restrict__ out) {
    __shared__ float As[64][17];
    __shared__ float Bs[64][17];
    int tx = threadIdx.x & 15, ty = threadIdx.x >> 4;
    int m0 = blockIdx.y * 64, n0 = blockIdx.x * 64;
    float acc[4][4] = {};
    for (int k0 = 0; k0 < Kdim; k0 += 16) {
#pragma unroll
        for (int i = 0; i < 4; ++i) {
            int idx = threadIdx.x + i * 256;
            int rr = idx >> 4, cc = idx & 15;
            As[rr][cc] = x[(size_t)(m0 + rr) * Kdim + k0 + cc];
            Bs[rr][cc] = w[(size_t)(n0 + rr) * Kdim + k0 + cc];
        }
        __syncthreads();
#pragma unroll
        for (int kk = 0; kk < 16; ++kk) {
            float a[4], b[4];
#pragma unroll
            for (int i = 0; i < 4; ++i) a[i] = As[ty * 4 + i][kk];
#pragma unroll
            for (int j = 0; j < 4; ++j) b[j] = Bs[tx * 4 + j][kk];
#pragma unroll
            for (int i = 0; i < 4; ++i)
#pragma unroll
                for (int j = 0; j < 4; ++j) acc[i][j] += a[i] * b[j];
        }
        __syncthreads();
    }
#pragma unroll
    for (int i = 0; i < 4; ++i)
#pragma unroll
        for (int j = 0; j < 4; ++j) {
            int gm = m0 + ty * 4 + i, gn = n0 + tx * 4 + j;
            out[(size_t)gm * Ndim + gn] = acc[i][j] + bias[gn];
        }
}

extern "C" void kernel_launch(void* const* d_in, const int* in_sizes, int n_in,
                              void* d_out, int out_size, void* d_ws, size_t ws_size,
                              hipStream_t stream) {
    const float* x    = (const float*)d_in[0];
    const float* w    = (const float*)d_in[1];
    const float* bias = (const float*)d_in[2];
    float* out        = (float*)d_out;

    const size_t needA = (size_t)Mdim * Kdim;            // 16.8 MB i8 image
    const size_t needB = (size_t)Ndim * Kdim;            //  4.2 MB i8 image
    const size_t needS = (Mdim + Ndim) * sizeof(float);  // scales

    if (ws_size >= needA + needB + needS) {
        signed char* xa  = (signed char*)d_ws;
        signed char* wbf = xa + needA;
        float* sx        = (float*)(wbf + needB);
        float* sw        = sx + Mdim;
        quantAB<<<Mdim + Ndim, 256, 0, stream>>>(x, w, xa, wbf, sx, sw);
        gemm13<<<(Mdim / 128) * (Ndim / 128), 256, 0, stream>>>(
            xa, wbf, sx, sw, bias, out);
    } else {
        dim3 grid(Ndim / 64, Mdim / 64);
        fallback_gemm<<<grid, 256, 0, stream>>>(x, w, bias, out);
    }
}

// Round 16
// 58.659 us; speedup vs baseline: 1.1052x; 1.1052x over previous
//
#include <hip/hip_runtime.h>

// ---------------------------------------------------------------------------
// AtomicLinear == x @ W^T + bias.  M=8192, N=2048, K=2048, fp32 in/out.
// R14: latency-hiding prefetch AT multi-block occupancy (the one untried
// combination).  128x128 tile, BK=64 i8 (32 K-tiles of 16 KB), LDS ring-3
// (48 KB -> 3 blocks/CU), STAGE(t+2) issued BEFORE compute(t), counted
// vmcnt(4) gates (never 0 mid-loop), raw s_barrier.  R13's XCD mapping
// (FETCH 70->33 MB, kept).  v_mfma_i32_16x16x64_i8, 4 waves 2Mx2N.
// Image swizzle for 64-B prows: slot = chunk ^ ((row>>1)&3)  (2-way = free).
// ---------------------------------------------------------------------------

typedef int i32x4 __attribute__((ext_vector_type(4)));

static constexpr int Mdim = 8192, Ndim = 2048, Kdim = 2048;
static constexpr int KT = 32;            // K-tiles of 64 i8
static constexpr int TB = 8192;          // tile: 128 rows x 64 i8
static constexpr int RING = 16384;       // per ring slot: A 8K + B 8K

// ---------------------------------------------------------------------------
// Fused quant prepass: block row < Mdim -> xa image, else -> wbf image.
// Per-row symmetric s = rowmax/127.  Image: tile (rt,kt) 8 KB; row r = prow
// (64 B); 16B chunk c (0..3) at slot = c ^ ((r>>1)&3).
// ---------------------------------------------------------------------------
__global__ void quantAB(const float* __restrict__ x, const float* __restrict__ w,
                        signed char* __restrict__ xa, signed char* __restrict__ wbf,
                        float* __restrict__ sx, float* __restrict__ sw) {
    const int rowg = blockIdx.x;
    const bool isA = rowg < Mdim;
    const int row  = isA ? rowg : rowg - Mdim;
    const float* src = (isA ? x : w) + (size_t)row * 2048;
    signed char* dst = isA ? xa : wbf;
    float* scale     = isA ? sx : sw;

    const int j = threadIdx.x;               // 0..255, elems k0 = j*8
    const int lane = j & 63, wid = j >> 6;
    const float* p = src + j * 8;
    float4 v0 = *(const float4*)p;
    float4 v1 = *(const float4*)(p + 4);
    float m = fmaxf(fmaxf(fmaxf(fabsf(v0.x), fabsf(v0.y)), fmaxf(fabsf(v0.z), fabsf(v0.w))),
                    fmaxf(fmaxf(fabsf(v1.x), fabsf(v1.y)), fmaxf(fabsf(v1.z), fabsf(v1.w))));
#pragma unroll
    for (int i = 1; i < 64; i <<= 1) m = fmaxf(m, __shfl_xor(m, i));
    __shared__ float wm[4];
    if (lane == 0) wm[wid] = m;
    __syncthreads();
    const float rm = fmaxf(fmaxf(wm[0], wm[1]), fmaxf(wm[2], wm[3]));
    const float qs = rm > 1e-30f ? 127.0f / rm : 0.0f;
    if (j == 0) scale[row] = rm > 1e-30f ? rm * (1.0f / 127.0f) : 0.0f;

    int q[8];
    q[0] = __float2int_rn(v0.x * qs); q[1] = __float2int_rn(v0.y * qs);
    q[2] = __float2int_rn(v0.z * qs); q[3] = __float2int_rn(v0.w * qs);
    q[4] = __float2int_rn(v1.x * qs); q[5] = __float2int_rn(v1.y * qs);
    q[6] = __float2int_rn(v1.z * qs); q[7] = __float2int_rn(v1.w * qs);
    uint2 pk;
    pk.x = (q[0] & 255) | ((q[1] & 255) << 8) | ((q[2] & 255) << 16) | ((unsigned)(q[3] & 255) << 24);
    pk.y = (q[4] & 255) | ((q[5] & 255) << 8) | ((q[6] & 255) << 16) | ((unsigned)(q[7] & 255) << 24);

    const int rt = row >> 7, r = row & 127;
    const int kt = j >> 3;                   // 0..31 (K-tile of 64)
    const int c  = (j & 7) >> 1;             // 16B chunk 0..3
    const int b8 = (j & 1) * 8;
    const int slot = c ^ ((r >> 1) & 3);
    size_t byte = (size_t)(rt * 32 + kt) * TB + r * 64 + (slot << 4) + b8;
    *(uint2*)(dst + byte) = pk;
}

#define GL_LDS16(gsrc, ldst)                                                    \
    __builtin_amdgcn_global_load_lds(                                           \
        (const __attribute__((address_space(1))) void*)(gsrc),                  \
        (__attribute__((address_space(3))) void*)(ldst), 16, 0, 0)

#define FENCE() asm volatile("" ::: "memory")

// 128x128 tile, 256 threads (4 waves 2M x 2N), wave tile 64x64.
__global__ __launch_bounds__(256) void gemm14(
    const signed char* __restrict__ xa, const signed char* __restrict__ wbf,
    const float* __restrict__ sx, const float* __restrict__ sw,
    const float* __restrict__ bias, float* __restrict__ out) {
    __shared__ signed char ring[3 * RING];   // [A 8K | B 8K] x 3

    const int tid  = threadIdx.x;
    const int lane = tid & 63, wid = tid >> 6;
    const int wr   = wid >> 1;               // 0..1
    const int wc   = wid & 1;                // 0..1
    const int fr   = lane & 15, fq = lane >> 4;

    // R13 XCD-locality mapping (validated: FETCH 70 -> 33 MB).
    const int bid = blockIdx.x;              // 1024 blocks
    const int xcd = bid & 7;
    const int s   = bid >> 3;                // 0..127
    const int nt  = s >> 3;                  // 0..15
    const int mt  = xcd * 8 + (s & 7);       // 0..63

    const signed char* aP = xa + (size_t)mt * KT * TB;
    const signed char* bP = wbf + (size_t)nt * KT * TB;

    // slot = fq ^ ((fr>>1)&3): lane-constant (row base multiple of 16).
    const int so = (fq ^ ((fr >> 1) & 3)) << 4;
    const int aBase = (wr * 64 + fr) * 64 + so;
    const int bBase = (wc * 64 + fr) * 64 + so;

    i32x4 acc[4][4];
#pragma unroll
    for (int i = 0; i < 4; ++i)
#pragma unroll
        for (int j = 0; j < 4; ++j)
            acc[i][j] = i32x4{0, 0, 0, 0};

#define STAGE(T, BUF)                                                           \
    {                                                                           \
        const signed char* gA = aP + (size_t)(T) * TB + tid * 16;               \
        const signed char* gB = bP + (size_t)(T) * TB + tid * 16;               \
        signed char* lb = ring + (BUF) * RING + tid * 16;                       \
        GL_LDS16(gA, lb);                                                       \
        GL_LDS16(gA + 4096, lb + 4096);                                         \
        GL_LDS16(gB, lb + 8192);                                                \
        GL_LDS16(gB + 4096, lb + 12288);                                        \
    }

#define COMPUTE(BUF)                                                            \
    {                                                                           \
        const signed char* sA = ring + (BUF) * RING;                            \
        const signed char* sB = sA + 8192;                                      \
        i32x4 a[4], b[4];                                                       \
        _Pragma("unroll")                                                       \
        for (int mi = 0; mi < 4; ++mi)                                          \
            a[mi] = *(const i32x4*)(sA + aBase + mi * 1024);                    \
        _Pragma("unroll")                                                       \
        for (int ni = 0; ni < 4; ++ni)                                          \
            b[ni] = *(const i32x4*)(sB + bBase + ni * 1024);                    \
        _Pragma("unroll")                                                       \
        for (int mi = 0; mi < 4; ++mi)                                          \
            _Pragma("unroll")                                                   \
            for (int ni = 0; ni < 4; ++ni)                                      \
                asm volatile("v_mfma_i32_16x16x64_i8 %0, %1, %2, %0"            \
                             : "+a"(acc[mi][ni]) : "v"(a[mi]), "v"(b[ni]));     \
    }

    // Prologue: stage tiles 0,1; wait tile0; barrier.
    STAGE(0, 0);
    STAGE(1, 1);
    asm volatile("s_waitcnt vmcnt(4)" ::: "memory");
    __builtin_amdgcn_s_barrier();
    FENCE();

    // Steady: t = 0..29 (10 iters x 3).  Issue STAGE(t+2) BEFORE compute(t);
    // counted vmcnt(4) waits tile t+1 only (t+2 stays in flight).
#pragma unroll 1
    for (int it = 0; it < 10; ++it) {
        const int t = 3 * it;
        STAGE(t + 2, 2); COMPUTE(0);
        asm volatile("s_waitcnt vmcnt(4)" ::: "memory");
        __builtin_amdgcn_s_barrier(); FENCE();
        STAGE(t + 3, 0); COMPUTE(1);
        asm volatile("s_waitcnt vmcnt(4)" ::: "memory");
        __builtin_amdgcn_s_barrier(); FENCE();
        STAGE(t + 4, 1); COMPUTE(2);
        asm volatile("s_waitcnt vmcnt(4)" ::: "memory");
        __builtin_amdgcn_s_barrier(); FENCE();
    }
    // Tail: t=30 (buf0; tile31 already staged), t=31 (buf1).
    COMPUTE(0);
    asm volatile("s_waitcnt vmcnt(0)" ::: "memory");
    __builtin_amdgcn_s_barrier(); FENCE();
    COMPUTE(1);
#undef STAGE
#undef COMPUTE

    // Epilogue: row = mt*128 + wr*64 + mi*16 + fq*4 + rr;
    //           col = nt*128 + wc*64 + ni*16 + fr.
    const int gr0 = mt * 128 + wr * 64 + fq * 4;
    const int gc0 = nt * 128 + wc * 64;
#pragma unroll
    for (int ni = 0; ni < 4; ++ni) {
        const int cn = gc0 + ni * 16 + fr;
        const float tv = sw[cn];
        const float bv = bias[cn];
#pragma unroll
        for (int mi = 0; mi < 4; ++mi) {
            const int rm = gr0 + mi * 16;
            const float4 sv = *(const float4*)&sx[rm];
            out[(size_t)(rm + 0) * Ndim + cn] = (float)acc[mi][ni][0] * sv.x * tv + bv;
            out[(size_t)(rm + 1) * Ndim + cn] = (float)acc[mi][ni][1] * sv.y * tv + bv;
            out[(size_t)(rm + 2) * Ndim + cn] = (float)acc[mi][ni][2] * sv.z * tv + bv;
            out[(size_t)(rm + 3) * Ndim + cn] = (float)acc[mi][ni][3] * sv.w * tv + bv;
        }
    }
}

// Correct-but-slow fp32 fallback if workspace is too small.
__global__ void fallback_gemm(const float* __restrict__ x, const float* __restrict__ w,
                              const float* __restrict__ bias, float* __restrict__ out) {
    __shared__ float As[64][17];
    __shared__ float Bs[64][17];
    int tx = threadIdx.x & 15, ty = threadIdx.x >> 4;
    int m0 = blockIdx.y * 64, n0 = blockIdx.x * 64;
    float acc[4][4] = {};
    for (int k0 = 0; k0 < Kdim; k0 += 16) {
#pragma unroll
        for (int i = 0; i < 4; ++i) {
            int idx = threadIdx.x + i * 256;
            int rr = idx >> 4, cc = idx & 15;
            As[rr][cc] = x[(size_t)(m0 + rr) * Kdim + k0 + cc];
            Bs[rr][cc] = w[(size_t)(n0 + rr) * Kdim + k0 + cc];
        }
        __syncthreads();
#pragma unroll
        for (int kk = 0; kk < 16; ++kk) {
            float a[4], b[4];
#pragma unroll
            for (int i = 0; i < 4; ++i) a[i] = As[ty * 4 + i][kk];
#pragma unroll
            for (int j = 0; j < 4; ++j) b[j] = Bs[tx * 4 + j][kk];
#pragma unroll
            for (int i = 0; i < 4; ++i)
#pragma unroll
                for (int j = 0; j < 4; ++j) acc[i][j] += a[i] * b[j];
        }
        __syncthreads();
    }
#pragma unroll
    for (int i = 0; i < 4; ++i)
#pragma unroll
        for (int j = 0; j < 4; ++j) {
            int gm = m0 + ty * 4 + i, gn = n0 + tx * 4 + j;
            out[(size_t)gm * Ndim + gn] = acc[i][j] + bias[gn];
        }
}

extern "C" void kernel_launch(void* const* d_in, const int* in_sizes, int n_in,
                              void* d_out, int out_size, void* d_ws, size_t ws_size,
                              hipStream_t stream) {
    const float* x    = (const float*)d_in[0];
    const float* w    = (const float*)d_in[1];
    const float* bias = (const float*)d_in[2];
    float* out        = (float*)d_out;

    const size_t needA = (size_t)Mdim * Kdim;            // 16.8 MB i8 image
    const size_t needB = (size_t)Ndim * Kdim;            //  4.2 MB i8 image
    const size_t needS = (Mdim + Ndim) * sizeof(float);  // scales

    if (ws_size >= needA + needB + needS) {
        signed char* xa  = (signed char*)d_ws;
        signed char* wbf = xa + needA;
        float* sx        = (float*)(wbf + needB);
        float* sw        = sx + Mdim;
        quantAB<<<Mdim + Ndim, 256, 0, stream>>>(x, w, xa, wbf, sx, sw);
        gemm14<<<(Mdim / 128) * (Ndim / 128), 256, 0, stream>>>(
            xa, wbf, sx, sw, bias, out);
    } else {
        dim3 grid(Ndim / 64, Mdim / 64);
        fallback_gemm<<<grid, 256, 0, stream>>>(x, w, bias, out);
    }
}